// Round 1
// baseline (97.872 us; speedup 1.0000x reference)
//
#include <hip/hip_runtime.h>

#define IW 512
#define IH 512
#define NPLANES 48
#define TX 128
#define TY 64
#define INR (TY + 10)   // 74 input rows per tile
#define BUFW 144

__device__ __forceinline__ int refl(int c) {
    c = (c < 0) ? -c : c;
    return (c > IW - 1) ? (2 * (IW - 1) - c) : c;
}

__launch_bounds__(64, 2)
__global__ void ssim_kernel(const float* __restrict__ img1,
                            const float* __restrict__ img2,
                            float* __restrict__ out)
{
    __shared__ float buf[2][2][BUFW];   // [slot][array][col], cols = [tx-8, tx+136)

    const int l  = threadIdx.x;          // 0..63
    const int tx = blockIdx.x * TX;
    const int ty = blockIdx.y * TY;
    const size_t pb = (size_t)blockIdx.z * (size_t)(IW * IH);
    const float* p1 = img1 + pb;
    const float* p2 = img2 + pb;
    float* po = out + pb;

    // kornia gaussian(11, 1.5), normalized
    const float gw[11] = {0.00102838f, 0.00759873f, 0.03600078f, 0.10936070f,
                          0.21300555f, 0.26601174f, 0.21300555f, 0.10936070f,
                          0.03600078f, 0.00759873f, 0.00102838f};

    // fixed per-lane staging columns (reflected once)
    const int rc0 = refl(tx - 8 + l);
    const int rc1 = refl(tx - 8 + 64 + l);
    const int rc2 = refl(tx - 8 + 128 + (l & 15));   // only lanes<16 used

    // rolling vertical accumulators: [slot mod 11][array][owned col 0/1]
    float acc[11][5][2];
    #pragma unroll
    for (int s = 0; s < 11; ++s) {
        #pragma unroll
        for (int a = 0; a < 5; ++a) { acc[s][a][0] = 0.f; acc[s][a][1] = 0.f; }
    }

    float nx1[3], nx2[3];
    nx1[2] = 0.f; nx2[2] = 0.f;
    {   // row 0 -> LDS slot 0
        const int r = refl(ty - 5);
        const float* r1 = p1 + (size_t)r * IW;
        const float* r2 = p2 + (size_t)r * IW;
        buf[0][0][l] = r1[rc0]; buf[0][0][64 + l] = r1[rc1];
        buf[0][1][l] = r2[rc0]; buf[0][1][64 + l] = r2[rc1];
        if (l < 16) { buf[0][0][128 + l] = r1[rc2]; buf[0][1][128 + l] = r2[rc2]; }
    }
    {   // row 1 -> regs
        const int r = refl(ty - 4);
        const float* r1 = p1 + (size_t)r * IW;
        const float* r2 = p2 + (size_t)r * IW;
        nx1[0] = r1[rc0]; nx1[1] = r1[rc1];
        nx2[0] = r2[rc0]; nx2[1] = r2[rc1];
        if (l < 16) { nx1[2] = r1[rc2]; nx2[2] = r2[rc2]; }
    }

    for (int hrb = 0; hrb < 77; hrb += 11) {     // row chunks of 11 (acc indices fold)
        #pragma unroll
        for (int jj = 0; jj < 11; ++jj) {
            const int hr = hrb + jj;             // uniform across wave
            if (hr < INR) {
                // ---- stage row hr+1 (in regs) into LDS slot (hr+1)&1 ----
                if (hr + 1 < INR) {
                    const int ws = (hr + 1) & 1;
                    buf[ws][0][l] = nx1[0]; buf[ws][0][64 + l] = nx1[1];
                    buf[ws][1][l] = nx2[0]; buf[ws][1][64 + l] = nx2[1];
                    if (l < 16) { buf[ws][0][128 + l] = nx1[2]; buf[ws][1][128 + l] = nx2[2]; }
                }
                // ---- issue global loads for row hr+2 ----
                if (hr + 2 < INR) {
                    const int r = refl(ty - 5 + hr + 2);
                    const float* r1 = p1 + (size_t)r * IW;
                    const float* r2 = p2 + (size_t)r * IW;
                    nx1[0] = r1[rc0]; nx1[1] = r1[rc1];
                    nx2[0] = r2[rc0]; nx2[1] = r2[rc1];
                    if (l < 16) { nx1[2] = r1[rc2]; nx2[2] = r2[rc2]; }
                }
                // ---- read this lane's window of row hr from LDS (aligned b64) ----
                const int rs = hr & 1;
                float2 a1[7], a2[7];             // floats [2l+2, 2l+16)
                const float* bp1 = &buf[rs][0][2 * l + 2];
                const float* bp2 = &buf[rs][1][2 * l + 2];
                #pragma unroll
                for (int i = 0; i < 7; ++i) {
                    a1[i] = *(const float2*)(bp1 + 2 * i);
                    a2[i] = *(const float2*)(bp2 + 2 * i);
                }
                #define A1e(i) (((i) & 1) ? a1[(i) >> 1].y : a1[(i) >> 1].x)
                #define A2e(i) (((i) & 1) ? a2[(i) >> 1].y : a2[(i) >> 1].x)

                // ---- products (shared between the 2 owned cols) ----
                float q11[12], q22[12], q12[12];  // for window idx i=1..12
                #pragma unroll
                for (int i = 1; i <= 12; ++i) {
                    const float x = A1e(i), y = A2e(i);
                    q11[i - 1] = x * x; q22[i - 1] = y * y; q12[i - 1] = x * y;
                }
                // ---- horizontal 11-tap for cols c0=tx+2l, c1=c0+1 ----
                float h00 = 0.f, h10 = 0.f, h20 = 0.f, h30 = 0.f, h40 = 0.f;
                float h01 = 0.f, h11 = 0.f, h21 = 0.f, h31 = 0.f, h41 = 0.f;
                #pragma unroll
                for (int k = 0; k < 11; ++k) {
                    const float w = gw[k];
                    h00 += w * A1e(1 + k); h10 += w * A2e(1 + k);
                    h20 += w * q11[k];     h30 += w * q22[k];     h40 += w * q12[k];
                    h01 += w * A1e(2 + k); h11 += w * A2e(2 + k);
                    h21 += w * q11[k + 1]; h31 += w * q22[k + 1]; h41 += w * q12[k + 1];
                }
                // ---- vertical rolling accumulation ----
                #pragma unroll
                for (int k = 0; k < 11; ++k) {
                    const int o = hr - k;               // uniform
                    if (o >= 0 && o < TY) {
                        const int s = ((jj - k) % 11 + 11) % 11;  // compile-time
                        const float w = gw[k];
                        acc[s][0][0] += w * h00; acc[s][0][1] += w * h01;
                        acc[s][1][0] += w * h10; acc[s][1][1] += w * h11;
                        acc[s][2][0] += w * h20; acc[s][2][1] += w * h21;
                        acc[s][3][0] += w * h30; acc[s][3][1] += w * h31;
                        acc[s][4][0] += w * h40; acc[s][4][1] += w * h41;
                    }
                }
                // ---- output row o = hr-10 completes at this input row ----
                if (hr >= 10) {
                    const int o = hr - 10;
                    const int sc = (jj + 1) % 11;       // compile-time
                    float res[2];
                    #pragma unroll
                    for (int c = 0; c < 2; ++c) {
                        const float mu1 = acc[sc][0][c], mu2 = acc[sc][1][c];
                        const float m11 = acc[sc][2][c], m22 = acc[sc][3][c], m12 = acc[sc][4][c];
                        const float mu1s = mu1 * mu1, mu2s = mu2 * mu2, mu12 = mu1 * mu2;
                        const float s1 = m11 - mu1s, s2 = m22 - mu2s, s12 = m12 - mu12;
                        const float num = (2.f * mu12 + 1e-4f) * (2.f * s12 + 9e-4f);
                        const float den = (mu1s + mu2s + 1e-4f) * (s1 + s2 + 9e-4f);
                        res[c] = num / (den + 1e-12f);
                    }
                    #pragma unroll
                    for (int a = 0; a < 5; ++a) { acc[sc][a][0] = 0.f; acc[sc][a][1] = 0.f; }
                    float2 st; st.x = res[0]; st.y = res[1];
                    *(float2*)&po[(size_t)(ty + o) * IW + tx + 2 * l] = st;
                }
            }
        }
    }
}

extern "C" void kernel_launch(void* const* d_in, const int* in_sizes, int n_in,
                              void* d_out, int out_size, void* d_ws, size_t ws_size,
                              hipStream_t stream) {
    const float* img1 = (const float*)d_in[0];
    const float* img2 = (const float*)d_in[1];
    float* out = (float*)d_out;
    dim3 grid(IW / TX, IH / TY, NPLANES);
    ssim_kernel<<<grid, dim3(64), 0, stream>>>(img1, img2, out);
}

// Round 2
// 90.668 us; speedup vs baseline: 1.0795x; 1.0795x over previous
//
#include <hip/hip_runtime.h>

#define IW 512
#define IH 512
#define NPLANES 48
#define TX 128
#define TY 32
#define INR (TY + 10)   // 42 input rows per tile
#define BUFW 144

typedef float f32x2 __attribute__((ext_vector_type(2)));

__device__ __forceinline__ f32x2 pk_mul(f32x2 a, f32x2 b) {
    f32x2 d;
    asm("v_pk_mul_f32 %0, %1, %2" : "=v"(d) : "v"(a), "v"(b));
    return d;
}
// weight (uniform) in SGPR pair as src1 — zero VGPR cost, 1-SGPR rule ok
__device__ __forceinline__ f32x2 pk_mul_s(f32x2 a, f32x2 w) {
    f32x2 d;
    asm("v_pk_mul_f32 %0, %1, %2" : "=v"(d) : "v"(a), "s"(w));
    return d;
}
__device__ __forceinline__ f32x2 pk_fma_s(f32x2 a, f32x2 w, f32x2 c) {
    f32x2 d;
    asm("v_pk_fma_f32 %0, %1, %2, %3" : "=v"(d) : "v"(a), "s"(w), "v"(c));
    return d;
}

__device__ __forceinline__ int refl(int c) {
    c = (c < 0) ? -c : c;
    return (c > IW - 1) ? (2 * (IW - 1) - c) : c;
}

__launch_bounds__(64, 3)
__global__ void ssim_kernel(const float* __restrict__ img1,
                            const float* __restrict__ img2,
                            float* __restrict__ out)
{
    __shared__ float buf[2][2][BUFW];   // [slot][array][col], cols = [tx-8, tx+136)

    const int l  = threadIdx.x;          // 0..63
    const int tx = blockIdx.x * TX;
    const int ty = blockIdx.y * TY;
    const size_t pb = (size_t)blockIdx.z * (size_t)(IW * IH);
    const float* p1 = img1 + pb;
    const float* p2 = img2 + pb;
    float* po = out + pb;

    // kornia gaussian(11, 1.5), normalized
    const float gw[11] = {0.00102838f, 0.00759873f, 0.03600078f, 0.10936070f,
                          0.21300555f, 0.26601174f, 0.21300555f, 0.10936070f,
                          0.03600078f, 0.00759873f, 0.00102838f};

    // fixed per-lane staging columns (reflected once)
    const int rc0 = refl(tx - 8 + l);
    const int rc1 = refl(tx - 8 + 64 + l);
    const int rc2 = refl(tx - 8 + 128 + (l & 15));   // only lanes<16 used

    // rolling vertical accumulators: [slot mod 11][array], packed over 2 owned cols
    f32x2 acc[11][5];
    #pragma unroll
    for (int s = 0; s < 11; ++s) {
        #pragma unroll
        for (int a = 0; a < 5; ++a) { acc[s][a].x = 0.f; acc[s][a].y = 0.f; }
    }

    float nx1[3], nx2[3];
    nx1[2] = 0.f; nx2[2] = 0.f;
    {   // row 0 -> LDS slot 0
        const int r = refl(ty - 5);
        const float* r1 = p1 + (size_t)r * IW;
        const float* r2 = p2 + (size_t)r * IW;
        buf[0][0][l] = r1[rc0]; buf[0][0][64 + l] = r1[rc1];
        buf[0][1][l] = r2[rc0]; buf[0][1][64 + l] = r2[rc1];
        if (l < 16) { buf[0][0][128 + l] = r1[rc2]; buf[0][1][128 + l] = r2[rc2]; }
    }
    {   // row 1 -> regs
        const int r = refl(ty - 4);
        const float* r1 = p1 + (size_t)r * IW;
        const float* r2 = p2 + (size_t)r * IW;
        nx1[0] = r1[rc0]; nx1[1] = r1[rc1];
        nx2[0] = r2[rc0]; nx2[1] = r2[rc1];
        if (l < 16) { nx1[2] = r1[rc2]; nx2[2] = r2[rc2]; }
    }

    for (int hrb = 0; hrb < 44; hrb += 11) {     // row chunks of 11 (acc indices fold)
        #pragma unroll
        for (int jj = 0; jj < 11; ++jj) {
            const int hr = hrb + jj;             // uniform across wave
            if (hr < INR) {
                // ---- stage row hr+1 (in regs) into LDS slot (hr+1)&1 ----
                if (hr + 1 < INR) {
                    const int ws = (hr + 1) & 1;
                    buf[ws][0][l] = nx1[0]; buf[ws][0][64 + l] = nx1[1];
                    buf[ws][1][l] = nx2[0]; buf[ws][1][64 + l] = nx2[1];
                    if (l < 16) { buf[ws][0][128 + l] = nx1[2]; buf[ws][1][128 + l] = nx2[2]; }
                }
                // ---- issue global loads for row hr+2 ----
                if (hr + 2 < INR) {
                    const int r = refl(ty - 5 + hr + 2);
                    const float* r1 = p1 + (size_t)r * IW;
                    const float* r2 = p2 + (size_t)r * IW;
                    nx1[0] = r1[rc0]; nx1[1] = r1[rc1];
                    nx2[0] = r2[rc0]; nx2[1] = r2[rc1];
                    if (l < 16) { nx1[2] = r1[rc2]; nx2[2] = r2[rc2]; }
                }
                // ---- read this lane's window of row hr from LDS (aligned b64) ----
                // a?[i] = { A(2i), A(2i+1) } where A(i) = buf_col(2l+2+i)
                const int rs = hr & 1;
                f32x2 a1[7], a2[7];
                const f32x2* bp1 = (const f32x2*)&buf[rs][0][2 * l + 2];
                const f32x2* bp2 = (const f32x2*)&buf[rs][1][2 * l + 2];
                #pragma unroll
                for (int i = 0; i < 7; ++i) { a1[i] = bp1[i]; a2[i] = bp2[i]; }

                // ---- horizontal 11-tap, packed over the 2 owned cols ----
                // X_k = {A(1+k), A(2+k)}; H = sum_k w_k (.) X_k  (and products)
                f32x2 H0, H1, H2, H3, H4;
                #pragma unroll
                for (int k = 0; k < 11; ++k) {
                    f32x2 X1, X2;
                    if (k & 1) {
                        X1 = a1[(k + 1) >> 1];
                        X2 = a2[(k + 1) >> 1];
                    } else {
                        X1.x = a1[k >> 1].y; X1.y = a1[(k >> 1) + 1].x;
                        X2.x = a2[k >> 1].y; X2.y = a2[(k >> 1) + 1].x;
                    }
                    const f32x2 w2 = {gw[k], gw[k]};
                    f32x2 Q11 = pk_mul(X1, X1);
                    f32x2 Q22 = pk_mul(X2, X2);
                    f32x2 Q12 = pk_mul(X1, X2);
                    if (k == 0) {
                        H0 = pk_mul_s(X1, w2);  H1 = pk_mul_s(X2, w2);
                        H2 = pk_mul_s(Q11, w2); H3 = pk_mul_s(Q22, w2);
                        H4 = pk_mul_s(Q12, w2);
                    } else {
                        H0 = pk_fma_s(X1, w2, H0);  H1 = pk_fma_s(X2, w2, H1);
                        H2 = pk_fma_s(Q11, w2, H2); H3 = pk_fma_s(Q22, w2, H3);
                        H4 = pk_fma_s(Q12, w2, H4);
                    }
                }

                // ---- vertical rolling accumulation ----
                #pragma unroll
                for (int k = 0; k < 11; ++k) {
                    const int o = hr - k;               // uniform
                    if (o >= 0 && o < TY) {
                        const int s = ((jj - k) % 11 + 11) % 11;  // compile-time
                        const f32x2 w2 = {gw[k], gw[k]};
                        acc[s][0] = pk_fma_s(H0, w2, acc[s][0]);
                        acc[s][1] = pk_fma_s(H1, w2, acc[s][1]);
                        acc[s][2] = pk_fma_s(H2, w2, acc[s][2]);
                        acc[s][3] = pk_fma_s(H3, w2, acc[s][3]);
                        acc[s][4] = pk_fma_s(H4, w2, acc[s][4]);
                    }
                }

                // ---- output row o = hr-10 completes at this input row ----
                if (hr >= 10) {
                    const int o = hr - 10;
                    const int sc = (jj + 1) % 11;       // compile-time
                    const f32x2 mu1 = acc[sc][0], mu2 = acc[sc][1];
                    const f32x2 m11 = acc[sc][2], m22 = acc[sc][3], m12 = acc[sc][4];
                    const f32x2 mu1s = mu1 * mu1, mu2s = mu2 * mu2, mu12 = mu1 * mu2;
                    const f32x2 s1 = m11 - mu1s, s2 = m22 - mu2s, s12 = m12 - mu12;
                    const f32x2 num = (2.f * mu12 + 1e-4f) * (2.f * s12 + 9e-4f);
                    const f32x2 den = (mu1s + mu2s + 1e-4f) * (s1 + s2 + 9e-4f);
                    const f32x2 res = num / (den + 1e-12f);
                    #pragma unroll
                    for (int a = 0; a < 5; ++a) { acc[sc][a].x = 0.f; acc[sc][a].y = 0.f; }
                    *(f32x2*)&po[(size_t)(ty + o) * IW + tx + 2 * l] = res;
                }
            }
        }
    }
}

extern "C" void kernel_launch(void* const* d_in, const int* in_sizes, int n_in,
                              void* d_out, int out_size, void* d_ws, size_t ws_size,
                              hipStream_t stream) {
    const float* img1 = (const float*)d_in[0];
    const float* img2 = (const float*)d_in[1];
    float* out = (float*)d_out;
    dim3 grid(IW / TX, IH / TY, NPLANES);
    ssim_kernel<<<grid, dim3(64), 0, stream>>>(img1, img2, out);
}

// Round 4
// 65.777 us; speedup vs baseline: 1.4879x; 1.3784x over previous
//
#include <hip/hip_runtime.h>
#include <stdint.h>

#define IW 512
#define IH 512
#define NPLANES 48
#define TX 128
#define TY 32
#define INR (TY + 10)   // 42 input rows per tile
#define BUFW 144        // staged cols [tx-8, tx+136)
#define SLOTS 8         // LDS ring slots (DMA depth 5, WAR gap 3)

typedef float f32x2 __attribute__((ext_vector_type(2)));

typedef __attribute__((address_space(1))) const uint32_t guint_t;
typedef __attribute__((address_space(3))) uint32_t luint_t;

// counted vmcnt wait, literal N, full compiler memory fence
#define WAITVM_(n) asm volatile("s_waitcnt vmcnt(" #n ")" ::: "memory")
#define WAITVM(n) WAITVM_(n)

// ---- packed-f32 helpers (VOP3P) ----
static __device__ __forceinline__ f32x2 pk_mul(f32x2 a, f32x2 b) {
    f32x2 d; asm("v_pk_mul_f32 %0, %1, %2" : "=v"(d) : "v"(a), "v"(b)); return d;
}
// normal packed fma, weight broadcast pair from SGPRs
static __device__ __forceinline__ f32x2 pk_fma_s(f32x2 a, f32x2 w, f32x2 c) {
    f32x2 d; asm("v_pk_fma_f32 %0, %1, %2, %3" : "=v"(d) : "v"(a), "s"(w), "v"(c)); return d;
}
// both result lanes use src0.hi:  d = {a.y*w.x, a.y*w.y}
static __device__ __forceinline__ f32x2 pk_mul_bh(f32x2 a, f32x2 w) {
    f32x2 d; asm("v_pk_mul_f32 %0, %1, %2 op_sel:[1,0] op_sel_hi:[1,1]"
                 : "=v"(d) : "v"(a), "s"(w)); return d;
}
static __device__ __forceinline__ f32x2 pk_fma_bh(f32x2 a, f32x2 w, f32x2 c) {
    f32x2 d; asm("v_pk_fma_f32 %0, %1, %2, %3 op_sel:[1,0,0] op_sel_hi:[1,1,1]"
                 : "=v"(d) : "v"(a), "s"(w), "v"(c)); return d;
}
// both result lanes use src0.lo:  d += {a.x*w.x, a.x*w.y}
static __device__ __forceinline__ f32x2 pk_fma_bl(f32x2 a, f32x2 w, f32x2 c) {
    f32x2 d; asm("v_pk_fma_f32 %0, %1, %2, %3 op_sel:[0,0,0] op_sel_hi:[0,1,1]"
                 : "=v"(d) : "v"(a), "s"(w), "v"(c)); return d;
}
static __device__ __forceinline__ float rcp_fast(float x) {
    float d; asm("v_rcp_f32 %0, %1" : "=v"(d) : "v"(x)); return d;
}

__device__ __forceinline__ int refl(int c) {
    c = (c < 0) ? -c : c;
    return (c > IW - 1) ? (2 * (IW - 1) - c) : c;
}

// gaussian(11, 1.5)
#define W0 0.00102838f
#define W1 0.00759873f
#define W2 0.03600078f
#define W3 0.10936070f
#define W4 0.21300555f
#define W5 0.26601174f
#define W6 0.21300555f
#define W7 0.10936070f
#define W8 0.03600078f
#define W9 0.00759873f
#define W10 0.00102838f

// One input-row step. JJ must be compile-time (acc slot index = fn(JJ)).
// ISSUE_D: stage row hr+5. WAITN: literal vmcnt count after issue.
#define SSIM_BODY(JJ, HR, ISSUE_D, WAITN)                                       \
  {                                                                             \
    const int hr = (HR);                                                        \
    const int rs = hr & 7;                                                      \
    if (ISSUE_D) {                                                              \
        const int rr = refl(ty - 5 + hr + 5);                                   \
        const int ws = (hr + 5) & 7;                                            \
        if (dmaok) {                                                            \
            __builtin_amdgcn_global_load_lds((guint_t*)(p1 + (size_t)rr * IW + gcol), \
                                             (luint_t*)&buf[ws][0][0], 16, 0, 0);     \
            __builtin_amdgcn_global_load_lds((guint_t*)(p2 + (size_t)rr * IW + gcol), \
                                             (luint_t*)&buf[ws][1][0], 16, 0, 0);     \
        }                                                                       \
    }                                                                           \
    WAITVM(WAITN);                                                              \
    /* read this lane's window: pairs a[i] = {A(2i), A(2i+1)}, A(i)=word 2l+2+i */ \
    f32x2 a1[7], a2[7];                                                         \
    {                                                                           \
        const f32x2* bp1 = (const f32x2*)&buf[rs][0][2 * l + 2];                \
        const f32x2* bp2 = (const f32x2*)&buf[rs][1][2 * l + 2];                \
        _Pragma("unroll")                                                       \
        for (int i = 0; i < 7; ++i) { a1[i] = bp1[i]; a2[i] = bp2[i]; }         \
    }                                                                           \
    /* border column-reflect fixups (read side) */                              \
    if (tx == 0) {                                                              \
        _Pragma("unroll")                                                       \
        for (int i = 1; i <= 5; ++i) {                                          \
            const int j = 2 * l + 2 + i;                                        \
            if (j < 8) {                                                        \
                const float v1 = buf[rs][0][16 - j];                            \
                const float v2 = buf[rs][1][16 - j];                            \
                if (i & 1) { a1[i >> 1].y = v1; a2[i >> 1].y = v2; }            \
                else       { a1[i >> 1].x = v1; a2[i >> 1].x = v2; }            \
            }                                                                   \
        }                                                                       \
    } else if (tx == IW - TX) {                                                 \
        _Pragma("unroll")                                                       \
        for (int i = 8; i <= 12; ++i) {                                         \
            const int j = 2 * l + 2 + i;                                        \
            if (j >= 136) {                                                     \
                const float v1 = buf[rs][0][270 - j];                           \
                const float v2 = buf[rs][1][270 - j];                           \
                if (i & 1) { a1[i >> 1].y = v1; a2[i >> 1].y = v2; }            \
                else       { a1[i >> 1].x = v1; a2[i >> 1].x = v2; }            \
            }                                                                   \
        }                                                                       \
    }                                                                           \
    /* horizontal 11-tap via op_sel broadcast fmas */                           \
    f32x2 H0, H1, H2, H3, H4;                                                   \
    {   /* i = 0: only hi element A(1) contributes */                           \
        const f32x2 Q11 = pk_mul(a1[0], a1[0]);                                 \
        const f32x2 Q22 = pk_mul(a2[0], a2[0]);                                 \
        const f32x2 Q12 = pk_mul(a1[0], a2[0]);                                 \
        H0 = pk_mul_bh(a1[0], WH[0]);                                           \
        H1 = pk_mul_bh(a2[0], WH[0]);                                           \
        H2 = pk_mul_bh(Q11,  WH[0]);                                            \
        H3 = pk_mul_bh(Q22,  WH[0]);                                            \
        H4 = pk_mul_bh(Q12,  WH[0]);                                            \
    }                                                                           \
    _Pragma("unroll")                                                           \
    for (int i = 1; i <= 5; ++i) {                                              \
        const f32x2 Q11 = pk_mul(a1[i], a1[i]);                                 \
        const f32x2 Q22 = pk_mul(a2[i], a2[i]);                                 \
        const f32x2 Q12 = pk_mul(a1[i], a2[i]);                                 \
        H0 = pk_fma_bl(a1[i], WL[i], H0); H0 = pk_fma_bh(a1[i], WH[i], H0);     \
        H1 = pk_fma_bl(a2[i], WL[i], H1); H1 = pk_fma_bh(a2[i], WH[i], H1);     \
        H2 = pk_fma_bl(Q11,  WL[i], H2); H2 = pk_fma_bh(Q11,  WH[i], H2);       \
        H3 = pk_fma_bl(Q22,  WL[i], H3); H3 = pk_fma_bh(Q22,  WH[i], H3);       \
        H4 = pk_fma_bl(Q12,  WL[i], H4); H4 = pk_fma_bh(Q12,  WH[i], H4);       \
    }                                                                           \
    {   /* i = 6: only lo element A(12) contributes */                          \
        const f32x2 Q11 = pk_mul(a1[6], a1[6]);                                 \
        const f32x2 Q22 = pk_mul(a2[6], a2[6]);                                 \
        const f32x2 Q12 = pk_mul(a1[6], a2[6]);                                 \
        H0 = pk_fma_bl(a1[6], WL[6], H0);                                       \
        H1 = pk_fma_bl(a2[6], WL[6], H1);                                       \
        H2 = pk_fma_bl(Q11,  WL[6], H2);                                        \
        H3 = pk_fma_bl(Q22,  WL[6], H3);                                        \
        H4 = pk_fma_bl(Q12,  WL[6], H4);                                        \
    }                                                                           \
    /* vertical rolling accumulation */                                         \
    _Pragma("unroll")                                                           \
    for (int k = 0; k < 11; ++k) {                                              \
        const int o = hr - k;               /* uniform */                       \
        if (o >= 0 && o < TY) {                                                 \
            const int s = (((JJ) - k) % 11 + 11) % 11;  /* compile-time */      \
            const f32x2 w2 = {gw[k], gw[k]};                                    \
            acc[s][0] = pk_fma_s(H0, w2, acc[s][0]);                            \
            acc[s][1] = pk_fma_s(H1, w2, acc[s][1]);                            \
            acc[s][2] = pk_fma_s(H2, w2, acc[s][2]);                            \
            acc[s][3] = pk_fma_s(H3, w2, acc[s][3]);                            \
            acc[s][4] = pk_fma_s(H4, w2, acc[s][4]);                            \
        }                                                                       \
    }                                                                           \
    /* output row o = hr-10 completes at this input row */                      \
    if (hr >= 10) {                                                             \
        const int o = hr - 10;                                                  \
        const int sc = ((JJ) + 1) % 11;       /* compile-time */                \
        const f32x2 mu1 = acc[sc][0], mu2 = acc[sc][1];                         \
        const f32x2 m11 = acc[sc][2], m22 = acc[sc][3], m12 = acc[sc][4];       \
        const f32x2 mu1s = mu1 * mu1, mu2s = mu2 * mu2, mu12 = mu1 * mu2;       \
        const f32x2 s1 = m11 - mu1s, s2 = m22 - mu2s, s12 = m12 - mu12;         \
        const f32x2 num = (2.f * mu12 + 1e-4f) * (2.f * s12 + 9e-4f);           \
        f32x2 den = (mu1s + mu2s + 1e-4f) * (s1 + s2 + 9e-4f);                  \
        den = den + 1e-12f;                                                     \
        f32x2 rd; rd.x = rcp_fast(den.x); rd.y = rcp_fast(den.y);               \
        rd = rd * (2.f - den * rd);         /* one Newton step */               \
        const f32x2 res = num * rd;                                             \
        _Pragma("unroll")                                                       \
        for (int a = 0; a < 5; ++a) { acc[sc][a].x = 0.f; acc[sc][a].y = 0.f; } \
        *(f32x2*)&po[(size_t)(ty + o) * IW + tx + 2 * l] = res;                 \
    }                                                                           \
  }

__launch_bounds__(64, 3)
__global__ void ssim_kernel(const float* __restrict__ img1,
                            const float* __restrict__ img2,
                            float* __restrict__ out)
{
    __shared__ float buf[SLOTS][2][BUFW];   // 9216 B; slot stride 1152 B

    const int l  = threadIdx.x;          // 0..63
    const int tx = blockIdx.x * TX;
    const int ty = blockIdx.y * TY;
    const size_t pb = (size_t)blockIdx.z * (size_t)(IW * IH);
    const float* p1 = img1 + pb;
    const float* p2 = img2 + pb;
    float* po = out + pb;

    const float gw[11] = {W0,W1,W2,W3,W4,W5,W6,W7,W8,W9,W10};
    // pair i = {A(2i),A(2i+1)}; H.x = sum_{k=1..11} w_{k-1}A(k); H.y = sum_{k=2..12} w_{k-2}A(k)
    // lo elem A(2i): weights {w_{2i-1}, w_{2i-2}};  hi elem A(2i+1): {w_{2i}, w_{2i-1}}
    const f32x2 WH[6] = { {W0, 0.f}, {W2, W1}, {W4, W3}, {W6, W5}, {W8, W7}, {W10, W9} };
    const f32x2 WL[7] = { {0.f,0.f}, {W1, W0}, {W3, W2}, {W5, W4}, {W7, W6}, {W9, W8}, {0.f, W10} };

    // ---- DMA lane setup: lane l (<36) stages 16B at cols [gcol, gcol+4) ----
    const int gcol = tx - 8 + 4 * l;
    const bool dmaok = (l < 36) && (gcol >= 0) && (gcol < IW);

    // ---- prologue: DMA rows 0..4 into slots 0..4 (depth 5) ----
    #pragma unroll
    for (int pr = 0; pr < 5; ++pr) {
        const int r = refl(ty - 5 + pr);
        if (dmaok) {
            __builtin_amdgcn_global_load_lds((guint_t*)(p1 + (size_t)r * IW + gcol),
                                             (luint_t*)&buf[pr][0][0], 16, 0, 0);
            __builtin_amdgcn_global_load_lds((guint_t*)(p2 + (size_t)r * IW + gcol),
                                             (luint_t*)&buf[pr][1][0], 16, 0, 0);
        }
    }

    // rolling vertical accumulators: [slot mod 11][array], packed over 2 owned cols
    f32x2 acc[11][5];
    #pragma unroll
    for (int s = 0; s < 11; ++s) {
        #pragma unroll
        for (int a = 0; a < 5; ++a) { acc[s][a].x = 0.f; acc[s][a].y = 0.f; }
    }

    // ---- main: hr = 0..32, always issue row hr+5, steady-state vmcnt(10) ----
    for (int hrb = 0; hrb < 33; hrb += 11) {
        #pragma unroll
        for (int jj = 0; jj < 11; ++jj) {
            SSIM_BODY(jj, hrb + jj, true, 10)
        }
    }
    // ---- tail: hr = 33..41 compile-time; drain vmcnt 10,10,10,10,8,6,4,2,0 ----
    SSIM_BODY(0, 33, true, 10)
    SSIM_BODY(1, 34, true, 10)
    SSIM_BODY(2, 35, true, 10)
    SSIM_BODY(3, 36, true, 10)
    SSIM_BODY(4, 37, false, 8)
    SSIM_BODY(5, 38, false, 6)
    SSIM_BODY(6, 39, false, 4)
    SSIM_BODY(7, 40, false, 2)
    SSIM_BODY(8, 41, false, 0)
}

extern "C" void kernel_launch(void* const* d_in, const int* in_sizes, int n_in,
                              void* d_out, int out_size, void* d_ws, size_t ws_size,
                              hipStream_t stream) {
    const float* img1 = (const float*)d_in[0];
    const float* img2 = (const float*)d_in[1];
    float* out = (float*)d_out;
    dim3 grid(IW / TX, IH / TY, NPLANES);
    ssim_kernel<<<grid, dim3(64), 0, stream>>>(img1, img2, out);
}